// Round 4
// baseline (90.772 us; speedup 1.0000x reference)
//
#include <hip/hip_runtime.h>
#include <hip/hip_bf16.h>
#include <math.h>

// PhaseMLP fused, R7: break the VMEM<->LDS pipe alternation.
//   y[b,o] = sum_k c_k(b) * ( x[b,:] @ W_k + b_k )
// R6 post-mortem: iteration body was VMW4 -> ds_read -> LGKM0 -> STAGE ->
// MFMA; the LGKM0-before-STAGE (same-slot overwrite) serialized the LDS and
// VMEM pipes per wave, and barrier-paced waves convoyed -> CU time became
// t_vm + t_lds + t_valu (~28us) instead of max(~10us).
// R7 iteration: STAGE(chunk i+1 -> OPPOSITE slot) -> vmcnt(4) -> ds_read
// (slot i) -> MFMA. The staged slot's reads completed last iteration
// (compiler lgkm-wait before last MFMA + program order), so no LGKM0 is
// needed and VMEM issue is continuous. Biases/phases are fully consumed in
// the prologue (per-lane Catmull regs + precomputed bias-mix bm = sum_k
// c_k*b_k), so epilogues have no global-load uses and the compiler emits no
// stream-draining waits there. LDS coeff table dropped.

typedef __attribute__((ext_vector_type(8))) short bf16x8;
typedef __attribute__((ext_vector_type(4))) float f32x4;

// LDS layout (bytes)
#define LDS_A0 0                    // 16 rows x 256B  = 4096
#define LDS_A1 4096                 // 16 rows x 512B  = 8192
#define LDS_A2 12288                // 16 rows x 512B  = 8192
#define LDS_B  20480                // 16 waves x 2 slots x 4096 = 131072
#define LDS_TOT (20480 + 131072)    // 151552 < 160K

#define VMW4()  asm volatile("s_waitcnt vmcnt(4)" ::: "memory")
#define VMW0()  asm volatile("s_waitcnt vmcnt(0)" ::: "memory")

static __device__ __forceinline__ void bar_keep_vmcnt() {
  asm volatile("s_waitcnt lgkmcnt(0)" ::: "memory");
  __builtin_amdgcn_s_barrier();
  asm volatile("" ::: "memory");
}

typedef const __attribute__((address_space(1))) unsigned char* gp1_t;
typedef __attribute__((address_space(3))) unsigned char* lp3_t;
static __device__ __forceinline__ void gl_lds16(const void* g, void* l) {
  __builtin_amdgcn_global_load_lds((gp1_t)g, (lp3_t)l, 16, 0, 0);
}

// stage one K=32 chunk (4 anchors x 1KB) of this wave's 16 columns.
// sb = per-lane source base: Wt + (colbase + (lane>>2))*ROWLEN + (lane&3)*8
// dst layout: [k][lane*16] ; lane covers (colL=lane>>2, qs=lane&3)
#define STAGE(sb, KIN, ci, slot) do {                                  \
    const unsigned short* _s = (sb) + (ci) * 32;                       \
    char* _d = myB + (slot) * 4096;                                    \
    gl_lds16(_s,             _d);                                      \
    gl_lds16(_s + (KIN),     _d + 1024);                               \
    gl_lds16(_s + 2 * (KIN), _d + 2048);                               \
    gl_lds16(_s + 3 * (KIN), _d + 3072);                               \
  } while (0)

static __device__ __forceinline__ unsigned short f2bf(float f) {
  union { float f; unsigned int u; } v; v.f = f;
  unsigned int r = v.u + 0x7fffu + ((v.u >> 16) & 1u);  // RNE
  return (unsigned short)(r >> 16);
}

// Catmull-Rom basis coeffs in ABSOLUTE anchor order (c[0..3] for anchors 0..3)
static __device__ __forceinline__ void catmull(float ph, float c[4]) {
  float t = 4.0f * ph;
  float ft = floorf(t);
  int i1 = ((int)ft) & 3;
  float w = t - ft;
  float w2 = w * w, w3 = w2 * w;
  float r0 = -0.5f * w + w2 - 0.5f * w3;
  float r1 = 1.0f - 2.5f * w2 + 1.5f * w3;
  float r2 = 0.5f * w + 2.0f * w2 - 1.5f * w3;
  float r3 = -0.5f * w2 + 0.5f * w3;
  c[(i1 + 3) & 3] = r0;
  c[i1]           = r1;
  c[(i1 + 1) & 3] = r2;
  c[(i1 + 2) & 3] = r3;
}

// ---------------------------------------------------------------------------
// Prep: transpose+convert all three weight tensors (fp32 [4K,O] -> bf16 [O,4K])
// ---------------------------------------------------------------------------
__global__ void k_wt_all(const float* __restrict__ w0, const float* __restrict__ w1,
                         const float* __restrict__ w2, unsigned short* __restrict__ t0,
                         unsigned short* __restrict__ t1, unsigned short* __restrict__ t2) {
  __shared__ float tile[32][33];
  int bid = blockIdx.x;
  const float* W; unsigned short* T; int R, C, idx;
  if (bid < 128)      { W = w0; T = t0; R = 512;  C = 256; idx = bid; }
  else if (bid < 384) { W = w1; T = t1; R = 1024; C = 256; idx = bid - 128; }
  else                { W = w2; T = t2; R = 1024; C = 128; idx = bid - 384; }
  int ntc = C >> 5;
  int tr = (idx / ntc) << 5;
  int tc = (idx % ntc) << 5;
  int tx = threadIdx.x, ty = threadIdx.y;  // (32,8)
#pragma unroll
  for (int j = ty; j < 32; j += 8)
    tile[j][tx] = W[(size_t)(tr + j) * C + (tc + tx)];
  __syncthreads();
#pragma unroll
  for (int j = ty; j < 32; j += 8)
    T[(size_t)(tc + j) * R + (tr + tx)] = f2bf(tile[tx][j]);
}

// mid-layer epilogue: anchor-combine + bias-mix + ELU, one bf16 write/row
static __device__ __forceinline__ void epi_mid(f32x4 a0, f32x4 a1, f32x4 a2, f32x4 a3,
                                               const float bm[4], const float cbr[4][4],
                                               int colg, int quad, char* outBuf) {
  const int g = colg >> 3;
  const int j2 = (colg & 7) * 2;
#pragma unroll
  for (int r = 0; r < 4; ++r) {
    const int m = quad * 4 + r;
    float y = cbr[r][0] * a0[r] + cbr[r][1] * a1[r] +
              cbr[r][2] * a2[r] + cbr[r][3] * a3[r] + bm[r];
    float a = y > 0.0f ? y : (__expf(y) - 1.0f);  // ELU
    *(unsigned short*)(outBuf + m * 512 + (((g ^ (m & 15)) << 4) + j2)) = f2bf(a);
  }
}

#define MFMA4()                                                            \
  acc0 = __builtin_amdgcn_mfma_f32_16x16x32_bf16(av, bv0, acc0, 0, 0, 0);  \
  acc1 = __builtin_amdgcn_mfma_f32_16x16x32_bf16(av, bv1, acc1, 0, 0, 0);  \
  acc2 = __builtin_amdgcn_mfma_f32_16x16x32_bf16(av, bv2, acc2, 0, 0, 0);  \
  acc3 = __builtin_amdgcn_mfma_f32_16x16x32_bf16(av, bv3, acc3, 0, 0, 0)

#define LOADB()                                                \
  bf16x8 bv0 = *(const bf16x8*)(bs + bOff);                    \
  bf16x8 bv1 = *(const bf16x8*)(bs + 1024 + bOff);             \
  bf16x8 bv2 = *(const bf16x8*)(bs + 2048 + bOff);             \
  bf16x8 bv3 = *(const bf16x8*)(bs + 3072 + bOff)

__global__ __launch_bounds__(1024, 4) void k_fused(
    const float* __restrict__ x, const float* __restrict__ phase,
    const unsigned short* __restrict__ Wt0, const float* __restrict__ b0,
    const unsigned short* __restrict__ Wt1, const float* __restrict__ b1,
    const unsigned short* __restrict__ Wt2, const float* __restrict__ b2,
    float* __restrict__ out) {
  __shared__ __align__(1024) char smem[LDS_TOT];

  const int tid = threadIdx.x;
  const int lane = tid & 63;
  const int wid = tid >> 6;     // 0..15
  const int col = lane & 15;    // MFMA row-of-A / col-of-B lane index
  const int quad = lane >> 4;
  const int m0 = blockIdx.x * 16;
  const int colg = wid * 16 + col;           // L0/L1 output column
  const int cg = wid & 7, kh = wid >> 3;     // L2: col-group + K-half
  const int colg2 = cg * 16 + col;
  const int hi16 = (col & 12) << 4;          // A-swizzle high bits
  const int lb = (quad ^ (col & 3)) << 4;    // A-swizzle low bits
  const int bOff = col * 64 + quad * 16;     // B chunk read offset (dense)

  char* myB = smem + LDS_B + wid * 8192;

  // per-lane staged-source bases (lane covers colL=lane>>2, qs=lane&3)
  const int colL = lane >> 2, qs = lane & 3;
  const unsigned short* sb0 = Wt0 + (size_t)(wid * 16 + colL) * 512 + qs * 8;
  const unsigned short* sb1 = Wt1 + (size_t)(wid * 16 + colL) * 1024 + qs * 8;
  const unsigned short* sb2 = Wt2 + (size_t)(cg * 16 + colL) * 1024 + kh * 128 + qs * 8;

  // ---- prologue loads: biases, phases, x — all consumed BEFORE the K-loops
  float bva[4], bvb[4], bvc[4];
#pragma unroll
  for (int k = 0; k < 4; ++k) {
    bva[k] = b0[k * 256 + colg];
    bvb[k] = b1[k * 256 + colg];
    bvc[k] = b2[k * 128 + colg2];
  }
  float ph[4];
#pragma unroll
  for (int r = 0; r < 4; ++r) ph[r] = phase[m0 + quad * 4 + r];

  float4 xv = {0.f, 0.f, 0.f, 0.f};
  if (tid < 512)
    xv = *(const float4*)(x + (size_t)(m0 + (tid >> 5)) * 128 + (tid & 31) * 4);

  // ---- start the weight stream (chunk 0 -> slot 0) ----
  STAGE(sb0, 128, 0, 0);

  // per-lane Catmull coeffs for its 4 rows + bias-mix per layer
  float cbr[4][4];
#pragma unroll
  for (int r = 0; r < 4; ++r) catmull(ph[r], cbr[r]);
  float bm0[4], bm1[4], bm2[4];
#pragma unroll
  for (int r = 0; r < 4; ++r) {
    bm0[r] = cbr[r][0] * bva[0] + cbr[r][1] * bva[1] + cbr[r][2] * bva[2] + cbr[r][3] * bva[3];
    bm1[r] = cbr[r][0] * bvb[0] + cbr[r][1] * bvb[1] + cbr[r][2] * bvb[2] + cbr[r][3] * bvb[3];
    bm2[r] = cbr[r][0] * bvc[0] + cbr[r][1] * bvc[1] + cbr[r][2] * bvc[2] + cbr[r][3] * bvc[3];
  }

  // ---- build A0: unscaled bf16 x, granule-swizzled (g ^ (row&15)) ----
  if (tid < 512) {
    const int row = tid >> 5, seg = tid & 31;
    const int g = seg >> 1, h = seg & 1;
    short4 hv;
    hv.x = (short)f2bf(xv.x); hv.y = (short)f2bf(xv.y);
    hv.z = (short)f2bf(xv.z); hv.w = (short)f2bf(xv.w);
    *(short4*)(smem + LDS_A0 + row * 256 + ((g ^ (row & 15)) << 4) + h * 8) = hv;
  }
  bar_keep_vmcnt();

  f32x4 acc0, acc1, acc2, acc3;

  // ---- layer 0: A0 (K=128 x 4 anchors) @ Wt0 -> A1. chunks 0..3 ----
  {
    acc0 = acc1 = acc2 = acc3 = (f32x4){0.f, 0.f, 0.f, 0.f};
    const char* aL = smem + LDS_A0 + col * 256 + lb;
#pragma unroll
    for (int i = 0; i < 4; ++i) {
      if (i < 3) STAGE(sb0, 128, i + 1, (i + 1) & 1);   // chunk i+1
      else       STAGE(sb1, 256, 0, 0);                 // chunk 4 (L1 c0)
      VMW4();                                           // chunk i ready
      const char* bs = myB + (i & 1) * 4096;
      bf16x8 av = *(const bf16x8*)(aL + ((i << 6) ^ hi16));
      LOADB();
      MFMA4();
    }
    epi_mid(acc0, acc1, acc2, acc3, bm0, cbr, colg, quad, smem + LDS_A1);
  }
  bar_keep_vmcnt();

  // ---- layer 1: A1 (K=256 x 4 anchors) @ Wt1 -> A2. chunks 4..11 ----
  {
    acc0 = acc1 = acc2 = acc3 = (f32x4){0.f, 0.f, 0.f, 0.f};
    const char* aL = smem + LDS_A1 + col * 512 + lb;
#pragma unroll
    for (int i = 0; i < 8; ++i) {
      if (i < 7) STAGE(sb1, 256, i + 1, (i + 1) & 1);   // chunk 5+i
      else       STAGE(sb2, 256, 0, 0);                 // chunk 12 (L2 c0)
      VMW4();
      const char* bs = myB + (i & 1) * 4096;
      bf16x8 av = *(const bf16x8*)(aL + ((i << 6) ^ hi16));
      LOADB();
      MFMA4();
    }
    epi_mid(acc0, acc1, acc2, acc3, bm1, cbr, colg, quad, smem + LDS_A2);
  }
  bar_keep_vmcnt();

  // ---- layer 2: A2 (K=256 x 4 anchors) @ Wt2 -> out fp32. chunks 12..15 ----
  {
    acc0 = acc1 = acc2 = acc3 = (f32x4){0.f, 0.f, 0.f, 0.f};
    const char* aL = smem + LDS_A2 + col * 512 + kh * 256 + lb;
#pragma unroll
    for (int i = 0; i < 4; ++i) {
      if (i < 3) { STAGE(sb2, 256, i + 1, (i + 1) & 1); VMW4(); }
      else       { VMW0(); }                            // final drain
      const char* bs = myB + (i & 1) * 4096;
      bf16x8 av = *(const bf16x8*)(aL + ((i << 6) ^ hi16));
      LOADB();
      MFMA4();
    }

    // anchor-combine partials
    float part[4];
#pragma unroll
    for (int r = 0; r < 4; ++r)
      part[r] = cbr[r][0] * acc0[r] + cbr[r][1] * acc1[r] +
                cbr[r][2] * acc2[r] + cbr[r][3] * acc3[r];

    // all gl_lds writes landed (VMW0 per wave) -> overlay reduce buf on Bst
    bar_keep_vmcnt();
    float* red = (float*)(smem + LDS_B);   // [8][16][17] = 8704 B
    if (kh) {
#pragma unroll
      for (int r = 0; r < 4; ++r)
        red[cg * 272 + (quad * 4 + r) * 17 + col] = part[r];
    }
    bar_keep_vmcnt();
    if (!kh) {
#pragma unroll
      for (int r = 0; r < 4; ++r) {
        const int m = quad * 4 + r;
        float y = part[r] + red[cg * 272 + m * 17 + col] + bm2[r];
        out[(size_t)(m0 + m) * 128 + colg2] = y;
      }
    }
  }
}

// ---------------------------------------------------------------------------
// ws layout: Wt0 @0 (256KB), Wt1 @256KB (512KB), Wt2 @768KB (256KB). 1 MB.
// ---------------------------------------------------------------------------
extern "C" void kernel_launch(void* const* d_in, const int* in_sizes, int n_in,
                              void* d_out, int out_size, void* d_ws, size_t ws_size,
                              hipStream_t stream) {
  const float* x     = (const float*)d_in[0];
  const float* phase = (const float*)d_in[1];
  const float* w0    = (const float*)d_in[2];
  const float* b0    = (const float*)d_in[3];
  const float* w1    = (const float*)d_in[4];
  const float* b1    = (const float*)d_in[5];
  const float* w2    = (const float*)d_in[6];
  const float* b2    = (const float*)d_in[7];
  float* out = (float*)d_out;

  char* ws = (char*)d_ws;
  unsigned short* Wt0 = (unsigned short*)ws;
  unsigned short* Wt1 = (unsigned short*)(ws + 262144);
  unsigned short* Wt2 = (unsigned short*)(ws + 262144 + 524288);

  k_wt_all<<<512, dim3(32, 8), 0, stream>>>(w0, w1, w2, Wt0, Wt1, Wt2);
  k_fused<<<256, 1024, 0, stream>>>(x, phase, Wt0, b0, Wt1, b1, Wt2, b2, out);
}